// Round 10
// baseline (176.452 us; speedup 1.0000x reference)
//
#include <hip/hip_runtime.h>
#include <math.h>

#define B 8
#define T 128
#define NKEY 127   // t-1
#define NPAD 128   // padded key count (score row 127 forced to prob 0)
#define KDIM 64    // Q_DIM == KV_DIM
#define NH 4       // heads
#define CH 256     // NH*KDIM output channels

typedef short short8 __attribute__((ext_vector_type(8)));   // 8 bf16 (4 VGPRs)
typedef float floatx4 __attribute__((ext_vector_type(4)));  // MFMA C/D

// tanh(x) = 1 - 2/(e^{2x}+1). Saturates correctly at +/-inf, no clamp needed.
__device__ __forceinline__ float fast_tanh(float x) {
    float e = __expf(2.f * x);
    float r = __builtin_amdgcn_rcpf(e + 1.f);
    return fmaf(-2.f, r, 1.f);
}

// Round-to-nearest-even bf16 x8 (hi-only path for both A and B fragments).
__device__ __forceinline__ void rne8(const float4& a, const float4& b, short8& hi) {
    float x[8] = {a.x, a.y, a.z, a.w, b.x, b.y, b.z, b.w};
    #pragma unroll
    for (int i = 0; i < 8; ++i) {
        unsigned u = __float_as_uint(x[i]);
        u += 0x7FFFu + ((u >> 16) & 1u);
        hi[i] = (short)(u >> 16);
    }
}

// One workgroup per (b,t): 8 waves (512 threads); two waves per head.
// R10 rationale: R8->R9 halved instruction work for -2% -- the kernel is
// latency-bound with every wave stalled ~96% and only 16 waves/CU resident.
// This round doubles TLP: 8-wave blocks at <=64 VGPRs give 4 blocks/CU x
// 8 waves = 32 waves/CU (VGPR<=64 is the 8-waves/SIMD boundary, m69; R9
// compiled to exactly 64). Wave (h,half): scores for nt = half*4..half*4+3,
// Phase B over n in [half*64, half*64+64). jt in 2 passes of 2 keeps live
// A-frags at 16 VGPRs so the 64-reg cap doesn't spill.
__global__ __launch_bounds__(512, 8)
void attn_kernel(const float* __restrict__ q_x,   // (B,T,64)
                 const float* __restrict__ kv_x,  // (B,T,127,64)
                 const float* __restrict__ Wk,    // (256,64)
                 const float* __restrict__ Wq,    // (256,64)
                 const float* __restrict__ Wv,    // (256,64)
                 const float* __restrict__ bias,  // (64,)
                 const float* __restrict__ Ws,    // (1,64)
                 const float* __restrict__ bs,    // (1,) -- cancels in softmax
                 float* __restrict__ out)         // (B,T,256)
{
    __shared__ __align__(16) short bh_lds[16][64][8];    // 16 KB: B-frag hi [chunk][lane][8]
    __shared__ float qb_lds[CH];                         // 1 KB: query+bias per channel
    __shared__ float p_lds[NH][NPAD];                    // 2 KB: scores then probs
    __shared__ __align__(16) float part_lds[NH][2][KDIM];// 2 KB: Phase-B partials
    __shared__ float invl_lds[NH];                       // 16 B -> ~21 KB total

    const int bt   = blockIdx.x;
    const int tid  = threadIdx.x;          // 0..511
    const int w    = tid >> 6;             // wave 0..7
    const int lane = tid & 63;
    const int h    = w >> 1;               // head 0..3 (two waves per head)
    const int half = w & 1;                // which half of the n-range
    const int col  = lane & 15;            // MFMA n/m lane index
    const int quad = lane >> 4;            // MFMA k-group / row-group

    const float* __restrict__ kvg = kv_x + (size_t)bt * NKEY * KDIM;

    // ---- convert kv (global) -> fragment-ordered bf16-hi LDS; 2 chunks/wave ----
    // chunk = nt*2+ks; write addr chunk*1024 + lane*16: lane-linear, 0 conflicts.
    // Fragment content: kv[nt*16 + col][ks*32 + quad*8 + j]
    #pragma unroll
    for (int c = 0; c < 2; ++c) {
        const int chunk = c * 8 + w;
        const int nt = chunk >> 1, ks = chunk & 1;
        const int n  = nt * 16 + col;
        const int k0 = ks * 32 + quad * 8;
        float4 a = make_float4(0.f, 0.f, 0.f, 0.f);
        float4 b = make_float4(0.f, 0.f, 0.f, 0.f);
        if (n < NKEY) {
            const float* p = kvg + (size_t)n * KDIM + k0;
            a = *(const float4*)p;
            b = *(const float4*)(p + 4);
        }
        short8 hi;
        rne8(a, b, hi);
        *(short8*)&bh_lds[chunk][lane][0] = hi;
    }

    // ---- query_j + bias -> qb_lds[channel] (waves 0-3; wave-uniform branch) ----
    if (tid < CH) {
        const float4* Wq4 = (const float4*)(Wq + (size_t)tid * KDIM);
        const float4* q4g = (const float4*)(q_x + (size_t)bt * KDIM);
        float4 qa = {0.f, 0.f, 0.f, 0.f};
        #pragma unroll
        for (int i = 0; i < 16; ++i) {
            float4 ww = Wq4[i];
            float4 q4 = q4g[i];
            qa.x = fmaf(q4.x, ww.x, qa.x);
            qa.y = fmaf(q4.y, ww.y, qa.y);
            qa.z = fmaf(q4.z, ww.z, qa.z);
            qa.w = fmaf(q4.w, ww.w, qa.w);
        }
        qb_lds[tid] = (qa.x + qa.y) + (qa.z + qa.w) + bias[tid & 63];
    }

    __syncthreads();   // B1: frags + qb ready

    // ---- scores for nt = half*4 .. half*4+3; jt in 2 passes of 2 ----
    float sp[4] = {0.f, 0.f, 0.f, 0.f};
    #pragma unroll
    for (int pass = 0; pass < 2; ++pass) {
        short8 ahi[2][2];
        float qbp[2][4], wsp[2][4];
        #pragma unroll
        for (int jj = 0; jj < 2; ++jj) {
            const int jt = pass * 2 + jj;
            #pragma unroll
            for (int ks = 0; ks < 2; ++ks) {
                const float* wrow = Wk + (size_t)(h * 64 + jt * 16 + col) * KDIM
                                       + ks * 32 + quad * 8;
                float4 a = *(const float4*)wrow;
                float4 b = *(const float4*)(wrow + 4);
                rne8(a, b, ahi[jj][ks]);
            }
            #pragma unroll
            for (int r = 0; r < 4; ++r) {
                const int j = jt * 16 + quad * 4 + r;
                qbp[jj][r] = qb_lds[h * 64 + j];
                wsp[jj][r] = Ws[j];
            }
        }
        #pragma unroll
        for (int ntl = 0; ntl < 4; ++ntl) {
            const int nt = half * 4 + ntl;
            short8 b0 = *(const short8*)&bh_lds[nt * 2 + 0][lane][0];
            short8 b1 = *(const short8*)&bh_lds[nt * 2 + 1][lane][0];
            #pragma unroll
            for (int jj = 0; jj < 2; ++jj) {
                floatx4 c = {0.f, 0.f, 0.f, 0.f};
                c = __builtin_amdgcn_mfma_f32_16x16x32_bf16(ahi[jj][0], b0, c, 0, 0, 0);
                c = __builtin_amdgcn_mfma_f32_16x16x32_bf16(ahi[jj][1], b1, c, 0, 0, 0);
                // D layout: col = n in tile, row = quad*4 + r = j in jt
                #pragma unroll
                for (int r = 0; r < 4; ++r)
                    sp[ntl] = fmaf(fast_tanh(c[r] + qbp[jj][r]), wsp[jj][r], sp[ntl]);
            }
        }
    }
    #pragma unroll
    for (int ntl = 0; ntl < 4; ++ntl) {
        float s = sp[ntl];
        s += __shfl_xor(s, 16, 64);   // reduce across quads (same col)
        s += __shfl_xor(s, 32, 64);
        if (lane < 16) p_lds[h][(half * 4 + ntl) * 16 + lane] = s;
    }

    __syncthreads();   // B2: all scores visible

    // ---- softmax per head (even wave of each head; wave-uniform branch) ----
    if (half == 0) {
        float s_a = p_lds[h][lane];
        float s_b = p_lds[h][64 + lane];
        if (lane == 63) s_b = -1e30f;          // mask pad row 127
        float mx = fmaxf(s_a, s_b);
        #pragma unroll
        for (int off = 32; off > 0; off >>= 1)
            mx = fmaxf(mx, __shfl_xor(mx, off, 64));
        float pa = __expf(s_a - mx);
        float pb = __expf(s_b - mx);           // lane 63 -> 0
        float ls = pa + pb;
        #pragma unroll
        for (int off = 32; off > 0; off >>= 1)
            ls += __shfl_xor(ls, off, 64);
        p_lds[h][lane]      = pa;              // unnormalized probs
        p_lds[h][64 + lane] = pb;              // p_lds[h][127] = 0 masks pad
        if (lane == 0) invl_lds[h] = 1.f / ls;
    }

    __syncthreads();   // B3: probs + invl visible

    // ---- Phase B: partial weighted kv over n in [half*64, half*64+64) ----
    // lane (col,quad): k = 4col..4col+3, rows n = half*64 + 4i + quad.
    // Coalesced dwordx4 global loads (L2/L3-hot), probs broadcast from LDS.
    {
        float4 a4 = make_float4(0.f, 0.f, 0.f, 0.f);
        #pragma unroll
        for (int i = 0; i < 16; ++i) {
            const int n = half * 64 + 4 * i + quad;
            const int n_eff = (n < NKEY) ? n : 0;      // row 127: p==0
            float4 v = *(const float4*)&kvg[(size_t)n_eff * KDIM + 4 * col];
            const float pn = p_lds[h][n];
            a4.x = fmaf(pn, v.x, a4.x);
            a4.y = fmaf(pn, v.y, a4.y);
            a4.z = fmaf(pn, v.z, a4.z);
            a4.w = fmaf(pn, v.w, a4.w);
        }
        a4.x += __shfl_xor(a4.x, 16, 64);  a4.y += __shfl_xor(a4.y, 16, 64);
        a4.z += __shfl_xor(a4.z, 16, 64);  a4.w += __shfl_xor(a4.w, 16, 64);
        a4.x += __shfl_xor(a4.x, 32, 64);  a4.y += __shfl_xor(a4.y, 32, 64);
        a4.z += __shfl_xor(a4.z, 32, 64);  a4.w += __shfl_xor(a4.w, 32, 64);
        if (lane < 16)
            *(float4*)&part_lds[h][half][4 * col] = a4;   // unnormalized
    }

    __syncthreads();   // B4: partials ready

    // ---- Phase C (waves 0-3): out[j] = (part0 + part1).Wv[j,:] * invl ----
    if (tid < CH) {
        const int j  = tid;
        const int hh = j >> 6;                 // uniform per wave
        const float inv = invl_lds[hh];
        const float4* Wv4 = (const float4*)(Wv + (size_t)j * KDIM);
        const float4* p0  = (const float4*)part_lds[hh][0];
        const float4* p1  = (const float4*)part_lds[hh][1];
        float4 oa = {0.f, 0.f, 0.f, 0.f};
        #pragma unroll
        for (int i = 0; i < 16; ++i) {
            float4 ww = Wv4[i];
            float4 c0 = p0[i];                 // broadcast
            float4 c1 = p1[i];
            float cx = c0.x + c1.x, cy = c0.y + c1.y;
            float cz = c0.z + c1.z, cw = c0.w + c1.w;
            oa.x = fmaf(cx, ww.x, oa.x);
            oa.y = fmaf(cy, ww.y, oa.y);
            oa.z = fmaf(cz, ww.z, oa.z);
            oa.w = fmaf(cw, ww.w, oa.w);
        }
        out[(size_t)bt * CH + j] = ((oa.x + oa.y) + (oa.z + oa.w)) * inv;
    }
}

extern "C" void kernel_launch(void* const* d_in, const int* in_sizes, int n_in,
                              void* d_out, int out_size, void* d_ws, size_t ws_size,
                              hipStream_t stream) {
    const float* q_x  = (const float*)d_in[0];
    const float* kv_x = (const float*)d_in[1];
    const float* Wk   = (const float*)d_in[2];
    const float* Wq   = (const float*)d_in[3];
    const float* Wv   = (const float*)d_in[4];
    const float* bias = (const float*)d_in[5];
    const float* Ws   = (const float*)d_in[6];
    const float* bs   = (const float*)d_in[7];
    float* out = (float*)d_out;

    attn_kernel<<<dim3(B * T), dim3(512), 0, stream>>>(
        q_x, kv_x, Wk, Wq, Wv, bias, Ws, bs, out);
}

// Round 11
// 155.325 us; speedup vs baseline: 1.1360x; 1.1360x over previous
//
#include <hip/hip_runtime.h>
#include <math.h>

#define B 8
#define T 128
#define NKEY 127   // t-1
#define NPAD 128   // padded key count (score row 127 forced to prob 0)
#define KDIM 64    // Q_DIM == KV_DIM
#define NH 4       // heads
#define CH 256     // NH*KDIM output channels

typedef short short8 __attribute__((ext_vector_type(8)));   // 8 bf16 (4 VGPRs)
typedef float floatx4 __attribute__((ext_vector_type(4)));  // MFMA C/D

// tanh(x) = 1 - 2/(e^{2x}+1). Saturates correctly at +/-inf, no clamp needed.
__device__ __forceinline__ float fast_tanh(float x) {
    float e = __expf(2.f * x);
    float r = __builtin_amdgcn_rcpf(e + 1.f);
    return fmaf(-2.f, r, 1.f);
}

// Round-to-nearest-even bf16 x8 (hi-only path for both A and B fragments).
__device__ __forceinline__ void rne8(const float4& a, const float4& b, short8& hi) {
    float x[8] = {a.x, a.y, a.z, a.w, b.x, b.y, b.z, b.w};
    #pragma unroll
    for (int i = 0; i < 8; ++i) {
        unsigned u = __float_as_uint(x[i]);
        u += 0x7FFFu + ((u >> 16) & 1u);
        hi[i] = (short)(u >> 16);
    }
}

// One block per (bt, head): 4096 blocks x 256 threads (4 waves).
// R11 rationale: R9 was latency-bound (all pipes <30%, waves stalled ~96%)
// with only 4 aligned blocks/CU. R10 proved launch_bounds arg2>2 caps VGPR
// at 256/arg2 -> spill. This round gets TLP via MORE, SMALLER blocks:
// 16 blocks/CU demand, per-wave work quartered (natural VGPR aimed <=64 =
// the 8-waves/SIMD boundary), phase-diverse blocks overlap each other's
// stalls. kv is re-read by 4 head-blocks but fits entirely in L3 (16.6 MB).
__global__ __launch_bounds__(256, 2)
void attn_kernel(const float* __restrict__ q_x,   // (B,T,64)
                 const float* __restrict__ kv_x,  // (B,T,127,64)
                 const float* __restrict__ Wk,    // (256,64)
                 const float* __restrict__ Wq,    // (256,64)
                 const float* __restrict__ Wv,    // (256,64)
                 const float* __restrict__ bias,  // (64,)
                 const float* __restrict__ Ws,    // (1,64)
                 const float* __restrict__ bs,    // (1,) -- cancels in softmax
                 float* __restrict__ out)         // (B,T,256)
{
    __shared__ __align__(16) short bh_lds[16][64][8];   // 16 KB: B-frag hi [chunk][lane][8]
    __shared__ float qb_lds[KDIM];                      // 256 B: query+bias (this head)
    __shared__ float p_lds[NPAD];                       // 512 B: scores then probs
    __shared__ __align__(16) float part_lds[4][KDIM];   // 1 KB: Phase-B partials
    __shared__ float invl_lds;                          // -> ~17.8 KB total

    const int idx  = blockIdx.x;           // 0..4095; consecutive = same bt
    const int bt   = idx >> 2;
    const int h    = idx & 3;              // this block's head
    const int tid  = threadIdx.x;          // 0..255
    const int wv   = tid >> 6;             // wave 0..3
    const int lane = tid & 63;
    const int col  = lane & 15;            // MFMA n/m lane index
    const int quad = lane >> 4;            // MFMA k-group / row-group

    const float* __restrict__ kvg = kv_x + (size_t)bt * NKEY * KDIM;

    // ---- convert kv (global/L3) -> fragment-ordered bf16-hi LDS; 4 chunks/wave ----
    // chunk = nt*2+ks; write addr chunk*1024 + lane*16: lane-linear, 0 conflicts.
    // Fragment content: kv[nt*16 + col][ks*32 + quad*8 + j]
    #pragma unroll
    for (int c = 0; c < 4; ++c) {
        const int chunk = c * 4 + wv;
        const int nt = chunk >> 1, ks = chunk & 1;
        const int n  = nt * 16 + col;
        const int k0 = ks * 32 + quad * 8;
        float4 a = make_float4(0.f, 0.f, 0.f, 0.f);
        float4 b = make_float4(0.f, 0.f, 0.f, 0.f);
        if (n < NKEY) {
            const float* p = kvg + (size_t)n * KDIM + k0;
            a = *(const float4*)p;
            b = *(const float4*)(p + 4);
        }
        short8 hi;
        rne8(a, b, hi);
        *(short8*)&bh_lds[chunk][lane][0] = hi;
    }

    // ---- qb for this head's 64 channels, split: wave wv does channels
    //      wv*16+col, k-quad = quad (16 k each), cross-quad shuffle reduce ----
    {
        const int c = wv * 16 + col;                     // channel within head
        const float* wrow = Wq + (size_t)(h * 64 + c) * KDIM + quad * 16;
        const float* qrow = q_x + (size_t)bt * KDIM + quad * 16;
        float s = 0.f;
        #pragma unroll
        for (int i = 0; i < 4; ++i) {
            float4 ww = ((const float4*)wrow)[i];
            float4 qq = ((const float4*)qrow)[i];
            s = fmaf(qq.x, ww.x, s); s = fmaf(qq.y, ww.y, s);
            s = fmaf(qq.z, ww.z, s); s = fmaf(qq.w, ww.w, s);
        }
        s += __shfl_xor(s, 16, 64);
        s += __shfl_xor(s, 32, 64);
        if (lane < 16) qb_lds[c] = s + bias[c];
    }

    __syncthreads();   // B1: frags + qb ready

    // ---- scores for nt = wv*2, wv*2+1; jt in 2 passes of 2 ----
    float sp[2] = {0.f, 0.f};
    #pragma unroll
    for (int pass = 0; pass < 2; ++pass) {
        short8 ahi[2][2];
        float qbp[2][4], wsp[2][4];
        #pragma unroll
        for (int jj = 0; jj < 2; ++jj) {
            const int jt = pass * 2 + jj;
            #pragma unroll
            for (int ks = 0; ks < 2; ++ks) {
                const float* wrow = Wk + (size_t)(h * 64 + jt * 16 + col) * KDIM
                                       + ks * 32 + quad * 8;
                float4 a = *(const float4*)wrow;
                float4 b = *(const float4*)(wrow + 4);
                rne8(a, b, ahi[jj][ks]);
            }
            #pragma unroll
            for (int r = 0; r < 4; ++r) {
                const int j = jt * 16 + quad * 4 + r;
                qbp[jj][r] = qb_lds[j];
                wsp[jj][r] = Ws[j];
            }
        }
        #pragma unroll
        for (int ntl = 0; ntl < 2; ++ntl) {
            const int nt = wv * 2 + ntl;
            short8 b0 = *(const short8*)&bh_lds[nt * 2 + 0][lane][0];
            short8 b1 = *(const short8*)&bh_lds[nt * 2 + 1][lane][0];
            #pragma unroll
            for (int jj = 0; jj < 2; ++jj) {
                floatx4 c = {0.f, 0.f, 0.f, 0.f};
                c = __builtin_amdgcn_mfma_f32_16x16x32_bf16(ahi[jj][0], b0, c, 0, 0, 0);
                c = __builtin_amdgcn_mfma_f32_16x16x32_bf16(ahi[jj][1], b1, c, 0, 0, 0);
                // D layout: col = n in tile, row = quad*4 + r = j in jt
                #pragma unroll
                for (int r = 0; r < 4; ++r)
                    sp[ntl] = fmaf(fast_tanh(c[r] + qbp[jj][r]), wsp[jj][r], sp[ntl]);
            }
        }
    }
    #pragma unroll
    for (int ntl = 0; ntl < 2; ++ntl) {
        float s = sp[ntl];
        s += __shfl_xor(s, 16, 64);   // reduce across quads (same col)
        s += __shfl_xor(s, 32, 64);
        if (lane < 16) p_lds[(wv * 2 + ntl) * 16 + col] = s;
    }

    __syncthreads();   // B2: all 128 scores visible

    // ---- softmax over 127 real keys (wave 0; 2 scores per lane) ----
    if (wv == 0) {
        float s_a = p_lds[lane];
        float s_b = p_lds[64 + lane];
        if (lane == 63) s_b = -1e30f;          // mask pad row 127
        float mx = fmaxf(s_a, s_b);
        #pragma unroll
        for (int off = 32; off > 0; off >>= 1)
            mx = fmaxf(mx, __shfl_xor(mx, off, 64));
        float pa = __expf(s_a - mx);
        float pb = __expf(s_b - mx);           // lane 63 -> 0
        float ls = pa + pb;
        #pragma unroll
        for (int off = 32; off > 0; off >>= 1)
            ls += __shfl_xor(ls, off, 64);
        p_lds[lane]      = pa;                 // unnormalized probs
        p_lds[64 + lane] = pb;                 // p_lds[127] = 0 masks pad
        if (lane == 0) invl_lds = 1.f / ls;
    }

    __syncthreads();   // B3: probs + invl visible

    // ---- Phase B: wave wv accumulates rows n = 32wv + 4i + quad over k=4col..4col+3
    //      (coalesced dwordx4 from global, L3-hot; probs broadcast from LDS) ----
    {
        float4 a4 = make_float4(0.f, 0.f, 0.f, 0.f);
        #pragma unroll
        for (int i = 0; i < 8; ++i) {
            const int n = 32 * wv + 4 * i + quad;
            const int n_eff = (n < NKEY) ? n : 0;      // row 127: p==0
            float4 v = *(const float4*)&kvg[(size_t)n_eff * KDIM + 4 * col];
            const float pn = p_lds[n];
            a4.x = fmaf(pn, v.x, a4.x);
            a4.y = fmaf(pn, v.y, a4.y);
            a4.z = fmaf(pn, v.z, a4.z);
            a4.w = fmaf(pn, v.w, a4.w);
        }
        a4.x += __shfl_xor(a4.x, 16, 64);  a4.y += __shfl_xor(a4.y, 16, 64);
        a4.z += __shfl_xor(a4.z, 16, 64);  a4.w += __shfl_xor(a4.w, 16, 64);
        a4.x += __shfl_xor(a4.x, 32, 64);  a4.y += __shfl_xor(a4.y, 32, 64);
        a4.z += __shfl_xor(a4.z, 32, 64);  a4.w += __shfl_xor(a4.w, 32, 64);
        if (lane < 16)
            *(float4*)&part_lds[wv][4 * col] = a4;      // unnormalized
    }

    __syncthreads();   // B4: partials ready

    // ---- Phase C: wave wv -> channels wv*16+col; k-quad split, shuffle reduce ----
    {
        const int c = wv * 16 + col;                    // channel within head
        const float inv = invl_lds;
        const float* wrow = Wv + (size_t)(h * 64 + c) * KDIM + quad * 16;
        float s = 0.f;
        #pragma unroll
        for (int i = 0; i < 4; ++i) {
            // wkv_unnorm[k] = sum over 4 wave-partials
            float4 p0 = ((const float4*)&part_lds[0][quad * 16])[i];
            float4 p1 = ((const float4*)&part_lds[1][quad * 16])[i];
            float4 p2 = ((const float4*)&part_lds[2][quad * 16])[i];
            float4 p3 = ((const float4*)&part_lds[3][quad * 16])[i];
            float4 ww = ((const float4*)wrow)[i];
            s = fmaf((p0.x + p1.x) + (p2.x + p3.x), ww.x, s);
            s = fmaf((p0.y + p1.y) + (p2.y + p3.y), ww.y, s);
            s = fmaf((p0.z + p1.z) + (p2.z + p3.z), ww.z, s);
            s = fmaf((p0.w + p1.w) + (p2.w + p3.w), ww.w, s);
        }
        s += __shfl_xor(s, 16, 64);
        s += __shfl_xor(s, 32, 64);
        if (lane < 16)
            out[(size_t)bt * CH + h * 64 + c] = s * inv;
    }
}

extern "C" void kernel_launch(void* const* d_in, const int* in_sizes, int n_in,
                              void* d_out, int out_size, void* d_ws, size_t ws_size,
                              hipStream_t stream) {
    const float* q_x  = (const float*)d_in[0];
    const float* kv_x = (const float*)d_in[1];
    const float* Wk   = (const float*)d_in[2];
    const float* Wq   = (const float*)d_in[3];
    const float* Wv   = (const float*)d_in[4];
    const float* bias = (const float*)d_in[5];
    const float* Ws   = (const float*)d_in[6];
    const float* bs   = (const float*)d_in[7];
    float* out = (float*)d_out;

    attn_kernel<<<dim3(B * T * NH), dim3(256), 0, stream>>>(
        q_x, kv_x, Wk, Wq, Wv, bias, Ws, bs, out);
}

// Round 12
// 127.773 us; speedup vs baseline: 1.3810x; 1.2156x over previous
//
#include <hip/hip_runtime.h>
#include <math.h>

#define B 8
#define T 128
#define NKEY 127   // t-1
#define NPAD 128   // padded key count (score row 127 forced to prob 0)
#define KDIM 64    // Q_DIM == KV_DIM
#define NH 4       // heads
#define CH 256     // NH*KDIM output channels

typedef short short8 __attribute__((ext_vector_type(8)));   // 8 bf16 (4 VGPRs)
typedef float floatx4 __attribute__((ext_vector_type(4)));  // MFMA C/D

// tanh(x) = 1 - 2/(e^{2x}+1). Saturates correctly at +/-inf, no clamp needed.
__device__ __forceinline__ float fast_tanh(float x) {
    float e = __expf(2.f * x);
    float r = __builtin_amdgcn_rcpf(e + 1.f);
    return fmaf(-2.f, r, 1.f);
}

// Round-to-nearest-even bf16 x8 (hi-only path for both A and B fragments).
__device__ __forceinline__ void rne8(const float4& a, const float4& b, short8& hi) {
    float x[8] = {a.x, a.y, a.z, a.w, b.x, b.y, b.z, b.w};
    #pragma unroll
    for (int i = 0; i < 8; ++i) {
        unsigned u = __float_as_uint(x[i]);
        u += 0x7FFFu + ((u >> 16) & 1u);
        hi[i] = (short)(u >> 16);
    }
}

// One workgroup per (b,t): 8 waves (512 threads); two waves per head.
// R12 = R10's structure (1024 blocks x 8 waves = 32 waves/CU static -- the
// TLP the latency-bound R9 lacked) with the spill fixed:
//  - __launch_bounds__(512,2): cap = 256/arg2 = 128 VGPR (R10's (512,8)
//    capped at 32 -> 160 MB scratch). R11 proved this work-split compiles
//    to ~44 natural VGPRs, which also clears the 64-reg 8-waves/SIMD line.
//  - one block per bt: kv read by exactly one block (R11's per-head blocks
//    quadrupled FETCH to 116 MB across XCD-private L2s).
// Wave (h,half): scores for nt = half*4..+3, Phase B n in [half*64,+64).
__global__ __launch_bounds__(512, 2)
void attn_kernel(const float* __restrict__ q_x,   // (B,T,64)
                 const float* __restrict__ kv_x,  // (B,T,127,64)
                 const float* __restrict__ Wk,    // (256,64)
                 const float* __restrict__ Wq,    // (256,64)
                 const float* __restrict__ Wv,    // (256,64)
                 const float* __restrict__ bias,  // (64,)
                 const float* __restrict__ Ws,    // (1,64)
                 const float* __restrict__ bs,    // (1,) -- cancels in softmax
                 float* __restrict__ out)         // (B,T,256)
{
    __shared__ __align__(16) short bh_lds[16][64][8];    // 16 KB: B-frag hi [chunk][lane][8]
    __shared__ float qb_lds[CH];                         // 1 KB: query+bias per channel
    __shared__ float p_lds[NH][NPAD];                    // 2 KB: scores then probs
    __shared__ __align__(16) float part_lds[NH][2][KDIM];// 2 KB: Phase-B partials
    __shared__ float invl_lds[NH];                       // 16 B -> ~21 KB total

    const int bt   = blockIdx.x;
    const int tid  = threadIdx.x;          // 0..511
    const int w    = tid >> 6;             // wave 0..7
    const int lane = tid & 63;
    const int h    = w >> 1;               // head 0..3 (two waves per head)
    const int half = w & 1;                // which half of the n-range
    const int col  = lane & 15;            // MFMA n/m lane index
    const int quad = lane >> 4;            // MFMA k-group / row-group

    const float* __restrict__ kvg = kv_x + (size_t)bt * NKEY * KDIM;

    // ---- convert kv (global) -> fragment-ordered bf16-hi LDS; 2 chunks/wave ----
    // chunk = nt*2+ks; write addr chunk*1024 + lane*16: lane-linear, 0 conflicts.
    // Fragment content: kv[nt*16 + col][ks*32 + quad*8 + j]
    #pragma unroll
    for (int c = 0; c < 2; ++c) {
        const int chunk = c * 8 + w;
        const int nt = chunk >> 1, ks = chunk & 1;
        const int n  = nt * 16 + col;
        const int k0 = ks * 32 + quad * 8;
        float4 a = make_float4(0.f, 0.f, 0.f, 0.f);
        float4 b = make_float4(0.f, 0.f, 0.f, 0.f);
        if (n < NKEY) {
            const float* p = kvg + (size_t)n * KDIM + k0;
            a = *(const float4*)p;
            b = *(const float4*)(p + 4);
        }
        short8 hi;
        rne8(a, b, hi);
        *(short8*)&bh_lds[chunk][lane][0] = hi;
    }

    // ---- query_j + bias -> qb_lds (all 8 waves: each does 32 channels via
    //      k-split: wave w covers channels (w>>1)*64 + half*32 + (lane>>1),
    //      2 lanes per channel, 32 k each; pairwise shuffle reduce) ----
    {
        const int c  = h * 64 + half * 32 + (lane >> 1);   // global channel
        const int k0 = (lane & 1) * 32;                    // this lane's k-half
        const float* wrow = Wq + (size_t)c * KDIM + k0;
        const float* qrow = q_x + (size_t)bt * KDIM + k0;
        float s = 0.f;
        #pragma unroll
        for (int i = 0; i < 8; ++i) {
            float4 ww = ((const float4*)wrow)[i];
            float4 qq = ((const float4*)qrow)[i];
            s = fmaf(qq.x, ww.x, s); s = fmaf(qq.y, ww.y, s);
            s = fmaf(qq.z, ww.z, s); s = fmaf(qq.w, ww.w, s);
        }
        s += __shfl_xor(s, 1, 64);                         // combine k-halves
        if ((lane & 1) == 0) qb_lds[c] = s + bias[c & 63];
    }

    __syncthreads();   // B1: frags + qb ready

    // ---- scores for nt = half*4 .. half*4+3; jt in 2 passes of 2 ----
    float sp[4] = {0.f, 0.f, 0.f, 0.f};
    #pragma unroll
    for (int pass = 0; pass < 2; ++pass) {
        short8 ahi[2][2];
        float qbp[2][4], wsp[2][4];
        #pragma unroll
        for (int jj = 0; jj < 2; ++jj) {
            const int jt = pass * 2 + jj;
            #pragma unroll
            for (int ks = 0; ks < 2; ++ks) {
                const float* wrow = Wk + (size_t)(h * 64 + jt * 16 + col) * KDIM
                                       + ks * 32 + quad * 8;
                float4 a = *(const float4*)wrow;
                float4 b = *(const float4*)(wrow + 4);
                rne8(a, b, ahi[jj][ks]);
            }
            #pragma unroll
            for (int r = 0; r < 4; ++r) {
                const int j = jt * 16 + quad * 4 + r;
                qbp[jj][r] = qb_lds[h * 64 + j];
                wsp[jj][r] = Ws[j];
            }
        }
        #pragma unroll
        for (int ntl = 0; ntl < 4; ++ntl) {
            const int nt = half * 4 + ntl;
            short8 b0 = *(const short8*)&bh_lds[nt * 2 + 0][lane][0];
            short8 b1 = *(const short8*)&bh_lds[nt * 2 + 1][lane][0];
            #pragma unroll
            for (int jj = 0; jj < 2; ++jj) {
                floatx4 c = {0.f, 0.f, 0.f, 0.f};
                c = __builtin_amdgcn_mfma_f32_16x16x32_bf16(ahi[jj][0], b0, c, 0, 0, 0);
                c = __builtin_amdgcn_mfma_f32_16x16x32_bf16(ahi[jj][1], b1, c, 0, 0, 0);
                // D layout: col = n in tile, row = quad*4 + r = j in jt
                #pragma unroll
                for (int r = 0; r < 4; ++r)
                    sp[ntl] = fmaf(fast_tanh(c[r] + qbp[jj][r]), wsp[jj][r], sp[ntl]);
            }
        }
    }
    #pragma unroll
    for (int ntl = 0; ntl < 4; ++ntl) {
        float s = sp[ntl];
        s += __shfl_xor(s, 16, 64);   // reduce across quads (same col)
        s += __shfl_xor(s, 32, 64);
        if (lane < 16) p_lds[h][(half * 4 + ntl) * 16 + lane] = s;
    }

    __syncthreads();   // B2: all scores visible

    // ---- softmax per head (even wave of each head; wave-uniform branch) ----
    if (half == 0) {
        float s_a = p_lds[h][lane];
        float s_b = p_lds[h][64 + lane];
        if (lane == 63) s_b = -1e30f;          // mask pad row 127
        float mx = fmaxf(s_a, s_b);
        #pragma unroll
        for (int off = 32; off > 0; off >>= 1)
            mx = fmaxf(mx, __shfl_xor(mx, off, 64));
        float pa = __expf(s_a - mx);
        float pb = __expf(s_b - mx);           // lane 63 -> 0
        float ls = pa + pb;
        #pragma unroll
        for (int off = 32; off > 0; off >>= 1)
            ls += __shfl_xor(ls, off, 64);
        p_lds[h][lane]      = pa;              // unnormalized probs
        p_lds[h][64 + lane] = pb;              // p_lds[h][127] = 0 masks pad
        if (lane == 0) invl_lds[h] = 1.f / ls;
    }

    __syncthreads();   // B3: probs + invl visible

    // ---- Phase B: partial weighted kv over n in [half*64, half*64+64) ----
    // lane (col,quad): k = 4col..4col+3, rows n = half*64 + 4i + quad.
    // Coalesced dwordx4 global loads (L2-hot), probs broadcast from LDS.
    {
        float4 a4 = make_float4(0.f, 0.f, 0.f, 0.f);
        #pragma unroll
        for (int i = 0; i < 16; ++i) {
            const int n = half * 64 + 4 * i + quad;
            const int n_eff = (n < NKEY) ? n : 0;      // row 127: p==0
            float4 v = *(const float4*)&kvg[(size_t)n_eff * KDIM + 4 * col];
            const float pn = p_lds[h][n];
            a4.x = fmaf(pn, v.x, a4.x);
            a4.y = fmaf(pn, v.y, a4.y);
            a4.z = fmaf(pn, v.z, a4.z);
            a4.w = fmaf(pn, v.w, a4.w);
        }
        a4.x += __shfl_xor(a4.x, 16, 64);  a4.y += __shfl_xor(a4.y, 16, 64);
        a4.z += __shfl_xor(a4.z, 16, 64);  a4.w += __shfl_xor(a4.w, 16, 64);
        a4.x += __shfl_xor(a4.x, 32, 64);  a4.y += __shfl_xor(a4.y, 32, 64);
        a4.z += __shfl_xor(a4.z, 32, 64);  a4.w += __shfl_xor(a4.w, 32, 64);
        if (lane < 16)
            *(float4*)&part_lds[h][half][4 * col] = a4;   // unnormalized
    }

    __syncthreads();   // B4: partials ready

    // ---- Phase C: all 8 waves; wave (h,half) does channels h*64+half*32+
    //      (lane>>1), k-halves split over lane parity, pairwise reduce ----
    {
        const int c  = h * 64 + half * 32 + (lane >> 1);   // global channel
        const int k0 = (lane & 1) * 32;
        const float inv = invl_lds[h];
        const float* wrow = Wv + (size_t)c * KDIM + k0;
        const float4* p0  = (const float4*)&part_lds[h][0][k0];
        const float4* p1  = (const float4*)&part_lds[h][1][k0];
        float s = 0.f;
        #pragma unroll
        for (int i = 0; i < 8; ++i) {
            float4 ww = ((const float4*)wrow)[i];
            float4 c0 = p0[i];
            float4 c1 = p1[i];
            s = fmaf(c0.x + c1.x, ww.x, s);
            s = fmaf(c0.y + c1.y, ww.y, s);
            s = fmaf(c0.z + c1.z, ww.z, s);
            s = fmaf(c0.w + c1.w, ww.w, s);
        }
        s += __shfl_xor(s, 1, 64);                         // combine k-halves
        if ((lane & 1) == 0)
            out[(size_t)bt * CH + c] = s * inv;
    }
}

extern "C" void kernel_launch(void* const* d_in, const int* in_sizes, int n_in,
                              void* d_out, int out_size, void* d_ws, size_t ws_size,
                              hipStream_t stream) {
    const float* q_x  = (const float*)d_in[0];
    const float* kv_x = (const float*)d_in[1];
    const float* Wk   = (const float*)d_in[2];
    const float* Wq   = (const float*)d_in[3];
    const float* Wv   = (const float*)d_in[4];
    const float* bias = (const float*)d_in[5];
    const float* Ws   = (const float*)d_in[6];
    const float* bs   = (const float*)d_in[7];
    float* out = (float*)d_out;

    attn_kernel<<<dim3(B * T), dim3(512), 0, stream>>>(
        q_x, kv_x, Wk, Wq, Wv, bias, Ws, bs, out);
}